// Round 1
// baseline (28340.945 us; speedup 1.0000x reference)
//
#include <hip/hip_runtime.h>

typedef unsigned short u16;
typedef short bf16x8 __attribute__((ext_vector_type(8)));
typedef float f32x4 __attribute__((ext_vector_type(4)));

#define SS 2048   // sequence length
#define BB 64     // batch
#define HH 512    // hidden
#define GG 2048   // 4*H gates

// ws layout (bytes)
#define WB_ELEMS (2048 * 1024)            // packed bf16 weight frags
#define OFF_BIAS ((size_t)WB_ELEMS * 2)   // 4,194,304
#define OFF_H0   (OFF_BIAS + 2048 * 4)    // 4,202,496  (h slot0, bf16)
#define OFF_H1   (OFF_H0 + 32768 * 2)     // 4,268,032  (h slot1, bf16)
#define OFF_CNT  (OFF_H1 + 32768 * 2)     // 4,333,568  (4 group barrier counters, 128B apart)
#define WS_NEED  (OFF_CNT + 512)          // 4,334,080 total

__device__ __forceinline__ u16 f2bf(float f) {
    unsigned int u = __builtin_bit_cast(unsigned int, f);
    u += 0x7FFFu + ((u >> 16) & 1u);   // round-to-nearest-even
    return (u16)(u >> 16);
}

// 8x f32 -> bf16x8 via v_cvt_pk_bf16_f32 (RNE), 4 instrs instead of ~24.
__device__ __forceinline__ bf16x8 pack8(float4 fa, float4 fb) {
    union { unsigned u[4]; bf16x8 v; } r;
    asm("v_cvt_pk_bf16_f32 %0, %1, %2" : "=v"(r.u[0]) : "v"(fa.x), "v"(fa.y));
    asm("v_cvt_pk_bf16_f32 %0, %1, %2" : "=v"(r.u[1]) : "v"(fa.z), "v"(fa.w));
    asm("v_cvt_pk_bf16_f32 %0, %1, %2" : "=v"(r.u[2]) : "v"(fb.x), "v"(fb.y));
    asm("v_cvt_pk_bf16_f32 %0, %1, %2" : "=v"(r.u[3]) : "v"(fb.z), "v"(fb.w));
    return r.v;
}

// Permuted gate index: p = w*32 + q*8 + (h&7), w = h>>3, q = gate (0=i,1=f,2=g,3=o).
// Packed B-frag layout: WB[gt][kc][lane][j], gt=0..127, kc=0..31,
// value = Wcat[p = gt*16 + (lane&15)][k = kc*32 + (lane>>4)*8 + j].
__global__ __launch_bounds__(256) void lstm_prep(
    const float* __restrict__ Wih, const float* __restrict__ Whh,
    const float* __restrict__ bih, const float* __restrict__ bhh,
    const float* __restrict__ h_prev,
    u16* __restrict__ WB, float* __restrict__ bias_p,
    u16* __restrict__ h0, unsigned* __restrict__ cnts)
{
    int idx = blockIdx.x * 256 + threadIdx.x;
    if (idx < WB_ELEMS) {
        int j    = idx & 7;
        int lane = (idx >> 3) & 63;
        int kc   = (idx >> 9) & 31;
        int gt   = idx >> 14;
        int p = gt * 16 + (lane & 15);
        int k = kc * 32 + (lane >> 4) * 8 + j;
        int q = (p >> 3) & 3;
        int h = ((p >> 5) << 3) | (p & 7);
        int row = q * 512 + h;
        float v = (k < 512) ? Wih[row * 512 + k] : Whh[row * 512 + (k - 512)];
        WB[idx] = f2bf(v);
    } else if (idx < WB_ELEMS + 2048) {
        int p = idx - WB_ELEMS;
        int q = (p >> 3) & 3;
        int h = ((p >> 5) << 3) | (p & 7);
        int row = q * 512 + h;
        bias_p[p] = bih[row] + bhh[row];
    } else if (idx < WB_ELEMS + 2048 + 32768) {
        int i = idx - (WB_ELEMS + 2048);
        h0[i] = f2bf(h_prev[i]);
    } else if (idx < WB_ELEMS + 2048 + 32768 + 128) {
        cnts[idx - (WB_ELEMS + 2048 + 32768)] = 0u;
    }
}

// Persistent LSTM. 64 blocks x 256 threads (4 waves). Block b: batch-tile bt = b&3
// (rows 16bt..16bt+16), waves cover hid-groups w = (b>>2)*4 + wave (0..63).
// 4 independent barrier groups (one per bt), 16 blocks each, monotonic counter.
// Weights (64KB/wave) live in VGPRs for all 2048 steps; c-state lives in registers.
__global__ __launch_bounds__(256, 1) void lstm_persist(
    const float* __restrict__ x_all, const u16* __restrict__ WB,
    const float* __restrict__ bias_p, const float* __restrict__ c_prev,
    u16* __restrict__ h0, u16* __restrict__ h1, unsigned* __restrict__ cnts,
    float* __restrict__ out, float* __restrict__ hf, float* __restrict__ cf)
{
    const int tid  = threadIdx.x;
    const int lane = tid & 63;
    const int wv   = tid >> 6;
    const int b    = blockIdx.x;
    const int bt   = b & 3;
    const int w    = (b >> 2) * 4 + wv;   // hid group 0..63
    const int b0   = bt * 16;
    const int col  = lane & 15;
    const int quad = lane >> 4;
    const bool lo  = (col & 8) == 0;

    unsigned* cnt = cnts + bt * 32;       // 128B-separated per group

    // ---- weights -> registers (once) ----
    bf16x8 wx0[16], wx1[16], wh0[16], wh1[16];
    {
        const u16* wb0 = WB + (size_t)(w * 2)     * (32 * 64 * 8) + lane * 8;
        const u16* wb1 = WB + (size_t)(w * 2 + 1) * (32 * 64 * 8) + lane * 8;
#pragma unroll
        for (int kc = 0; kc < 16; ++kc) {
            wx0[kc] = *(const bf16x8*)(wb0 + (size_t)kc * 512);
            wx1[kc] = *(const bf16x8*)(wb1 + (size_t)kc * 512);
            wh0[kc] = *(const bf16x8*)(wb0 + (size_t)(kc + 16) * 512);
            wh1[kc] = *(const bf16x8*)(wb1 + (size_t)(kc + 16) * 512);
        }
    }

    const int hid  = (w << 3) | (col & 7);
    const float blo = bias_p[w * 32 + col];
    const float bhi = bias_p[w * 32 + 16 + col];

    // each lane owns 2 C-rows: quad*4 + {0,1} (lo) or quad*4 + {2,3} (hi)
    const int row0 = quad * 4 + (lo ? 0 : 2);
    float creg[2];
#pragma unroll
    for (int rr = 0; rr < 2; ++rr)
        creg[rr] = c_prev[(size_t)(b0 + row0 + rr) * 512 + hid];

    const int ba = b0 + col;                               // A-frag row m = lane&15
    const float* xbase = x_all + (size_t)ba * 512 + quad * 8;
    const u16* h0row = h0 + ba * 512 + quad * 8;
    const u16* h1row = h1 + ba * 512 + quad * 8;

    for (int t = 0; t < SS; ++t) {
        f32x4 acc0 = {0.f, 0.f, 0.f, 0.f};
        f32x4 acc1 = {0.f, 0.f, 0.f, 0.f};

        // ---- x-part (independent of recurrence; overlaps barrier slack) ----
        const float* xrow = xbase + (size_t)t * (BB * 512);
#pragma unroll
        for (int kc = 0; kc < 16; ++kc) {
            float4 fa = *(const float4*)(xrow + kc * 32);
            float4 fb = *(const float4*)(xrow + kc * 32 + 4);
            bf16x8 a = pack8(fa, fb);
            acc0 = __builtin_amdgcn_mfma_f32_16x16x32_bf16(a, wx0[kc], acc0, 0, 0, 0);
            acc1 = __builtin_amdgcn_mfma_f32_16x16x32_bf16(a, wx1[kc], acc1, 0, 0, 0);
        }

        // ---- wait for h_{t} (generation t): 16 arrivals/group/step ----
        if (t) {
            const unsigned target = (unsigned)(16 * t);
            unsigned guard = 0;
            while (__hip_atomic_load(cnt, __ATOMIC_RELAXED, __HIP_MEMORY_SCOPE_AGENT) < target) {
                if (++guard > (1u << 20)) break;   // fail loud (wrong results), never deadlock
            }
            __builtin_amdgcn_fence(__ATOMIC_ACQUIRE, "agent");
        }

        // ---- h-part ----
        const u16* hrow = (t & 1) ? h1row : h0row;
#pragma unroll
        for (int kc = 0; kc < 16; ++kc) {
            bf16x8 a = *(const bf16x8*)(hrow + kc * 32);
            acc0 = __builtin_amdgcn_mfma_f32_16x16x32_bf16(a, wh0[kc], acc0, 0, 0, 0);
            acc1 = __builtin_amdgcn_mfma_f32_16x16x32_bf16(a, wh1[kc], acc1, 0, 0, 0);
        }

        // ---- epilogue: full-exec. acc0 = (i|f), acc1 = (g|o) by col half. ----
        float act0[4], act1[4];
#pragma unroll
        for (int r = 0; r < 4; ++r) {
            float v0 = acc0[r] + blo;
            float v1 = acc1[r] + bhi;
            act0[r] = 1.f / (1.f + __expf(-v0));                   // sigmoid(i) or sigmoid(f)
            float kk = lo ? 2.f : 1.f;
            float e = 1.f / (1.f + __expf(-kk * v1));
            act1[r] = lo ? (2.f * e - 1.f) : e;                    // tanh(g) or sigmoid(o)
        }
        float p0[4], p1[4];
#pragma unroll
        for (int r = 0; r < 4; ++r) {
            p0[r] = __shfl_xor(act0[r], 8);
            p1[r] = __shfl_xor(act1[r], 8);
        }
        u16* hout = (t & 1) ? h0 : h1;
        const bool lastt = (t == SS - 1);
#pragma unroll
        for (int rr = 0; rr < 2; ++rr) {
            float i_ = lo ? act0[rr] : p0[rr + 2];
            float f_ = lo ? p0[rr]   : act0[rr + 2];
            float g_ = lo ? act1[rr] : p1[rr + 2];
            float o_ = lo ? p1[rr]   : act1[rr + 2];
            float c_new = f_ * creg[rr] + i_ * g_;
            float tc = 2.f / (1.f + __expf(-2.f * c_new)) - 1.f;
            float h_new = o_ * tc;
            creg[rr] = c_new;
            int idx = (b0 + row0 + rr) * 512 + hid;
            hout[idx] = f2bf(h_new);
            out[(size_t)t * (BB * HH) + idx] = h_new;
            if (lastt) { hf[idx] = h_new; cf[idx] = c_new; }
        }

        // ---- arrive: one release per block ----
        __syncthreads();                      // drains each wave's stores to L2
        if (tid == 0) {
            __builtin_amdgcn_fence(__ATOMIC_RELEASE, "agent");   // wbL2 -> agent visibility
            __hip_atomic_fetch_add(cnt, 1u, __ATOMIC_RELAXED, __HIP_MEMORY_SCOPE_AGENT);
        }
    }
}

extern "C" void kernel_launch(void* const* d_in, const int* in_sizes, int n_in,
                              void* d_out, int out_size, void* d_ws, size_t ws_size,
                              hipStream_t stream) {
    const float* x      = (const float*)d_in[0];
    const float* h_prev = (const float*)d_in[1];
    const float* c_prev = (const float*)d_in[2];
    const float* Wih    = (const float*)d_in[3];
    const float* Whh    = (const float*)d_in[4];
    const float* bih    = (const float*)d_in[5];
    const float* bhh    = (const float*)d_in[6];
    float* out = (float*)d_out;

    if (ws_size < WS_NEED) return;  // cannot run without scratch

    char* ws = (char*)d_ws;
    u16*      WB     = (u16*)ws;
    float*    bias_p = (float*)(ws + OFF_BIAS);
    u16*      h0     = (u16*)(ws + OFF_H0);
    u16*      h1     = (u16*)(ws + OFF_H1);
    unsigned* cnts   = (unsigned*)(ws + OFF_CNT);

    int prep_threads = WB_ELEMS + 2048 + 32768 + 128;
    int prep_blocks = (prep_threads + 255) / 256;
    hipLaunchKernelGGL(lstm_prep, dim3(prep_blocks), dim3(256), 0, stream,
                       Wih, Whh, bih, bhh, h_prev, WB, bias_p, h0, cnts);

    float* hf = out + (size_t)SS * BB * HH;
    float* cf = hf + BB * HH;

    void* args[] = {
        (void*)&x, (void*)&WB, (void*)&bias_p, (void*)&c_prev,
        (void*)&h0, (void*)&h1, (void*)&cnts,
        (void*)&out, (void*)&hf, (void*)&cf
    };
    hipError_t err = hipLaunchCooperativeKernel(
        reinterpret_cast<void*>(lstm_persist), dim3(64), dim3(256), args, 0, stream);
    if (err != hipSuccess) {
        // 64 blocks x 256 thr (<=512 VGPR) = 1 block/CU on a 256-CU idle chip:
        // co-resident regardless; plain launch as fallback.
        hipLaunchKernelGGL(lstm_persist, dim3(64), dim3(256), 0, stream,
                           x, WB, bias_p, c_prev, h0, h1, cnts, out, hf, cf);
    }
}

// Round 2
// 13503.809 us; speedup vs baseline: 2.0987x; 2.0987x over previous
//
#include <hip/hip_runtime.h>

typedef unsigned short u16;
typedef short bf16x8 __attribute__((ext_vector_type(8)));
typedef float f32x4 __attribute__((ext_vector_type(4)));

#define SS 2048   // sequence length
#define BB 64     // batch
#define HH 512    // hidden
#define GG 2048   // 4*H gates

// ws layout (bytes)
#define WB_ELEMS (2048 * 1024)            // packed bf16 weight frags (4 MB)
#define OFF_BIAS ((size_t)WB_ELEMS * 2)   // 4,194,304
#define OFF_H0   (OFF_BIAS + 2048 * 4)    // 4,202,496  (h slot0, bf16 [64][512])
#define OFF_H1   (OFF_H0 + 32768 * 2)     // 4,268,032  (h slot1)
#define OFF_CNT  (OFF_H1 + 32768 * 2)     // 4,333,568  (4 barrier counters, 128B apart)
#define WS_BASE  (OFF_CNT + 512)          // 4,334,080
#define OFF_XBF  WS_BASE                  // optional bf16 x (128 MB)
#define WS_XBF   (OFF_XBF + (size_t)SS * BB * 512 * 2)   // 138,551,808

__device__ __forceinline__ u16 f2bf(float f) {
    unsigned int u = __builtin_bit_cast(unsigned int, f);
    u += 0x7FFFu + ((u >> 16) & 1u);   // round-to-nearest-even
    return (u16)(u >> 16);
}

// 8x f32 -> bf16x8 via v_cvt_pk_bf16_f32 (RNE)
__device__ __forceinline__ bf16x8 pack8(float4 fa, float4 fb) {
    union { unsigned u[4]; bf16x8 v; } r;
    asm("v_cvt_pk_bf16_f32 %0, %1, %2" : "=v"(r.u[0]) : "v"(fa.x), "v"(fa.y));
    asm("v_cvt_pk_bf16_f32 %0, %1, %2" : "=v"(r.u[1]) : "v"(fa.z), "v"(fa.w));
    asm("v_cvt_pk_bf16_f32 %0, %1, %2" : "=v"(r.u[2]) : "v"(fb.x), "v"(fb.y));
    asm("v_cvt_pk_bf16_f32 %0, %1, %2" : "=v"(r.u[3]) : "v"(fb.z), "v"(fb.w));
    return r.v;
}

// Coherent (LLC-level) 16B load: bypasses L1+L2 so cross-XCD producer data is seen.
// NOTE: completion NOT waited here — caller must s_waitcnt vmcnt(0) + sched_barrier(0).
__device__ __forceinline__ void load_coh_b128(bf16x8* dst, const void* p) {
    asm volatile("global_load_dwordx4 %0, %1, off sc0 sc1" : "=v"(*dst) : "v"(p));
}

// Gate permutation: column p = gt*16 + q*4 + (h&3), gt = h>>2 (tile of 4 hids),
// q = gate (0=i,1=f,2=g,3=o). All 4 gates of a hid live in ONE 16-col tile.
// decode: gt = p>>4; q = (p>>2)&3; h = gt*4 + (p&3); original row = q*512 + h.
// Packed B-frag: WB[gt][kc][lane][j] = Wcat[p = gt*16 + (lane&15)][k = kc*32 + (lane>>4)*8 + j],
// Wcat[p][k] = k<512 ? Wih[row(p)][k] : Whh[row(p)][k-512].
__global__ __launch_bounds__(256) void lstm_prep(
    const float* __restrict__ Wih, const float* __restrict__ Whh,
    const float* __restrict__ bih, const float* __restrict__ bhh,
    const float* __restrict__ h_prev,
    u16* __restrict__ WB, float* __restrict__ bias_p,
    u16* __restrict__ h0, unsigned* __restrict__ cnts)
{
    int idx = blockIdx.x * 256 + threadIdx.x;
    if (idx < WB_ELEMS) {
        int j    = idx & 7;
        int lane = (idx >> 3) & 63;
        int kc   = (idx >> 9) & 31;
        int gt   = idx >> 14;
        int p = gt * 16 + (lane & 15);
        int k = kc * 32 + (lane >> 4) * 8 + j;
        int q = (p >> 2) & 3;
        int h = (p >> 4) * 4 + (p & 3);
        int row = q * 512 + h;
        float v = (k < 512) ? Wih[row * 512 + k] : Whh[row * 512 + (k - 512)];
        WB[idx] = f2bf(v);
    } else if (idx < WB_ELEMS + 2048) {
        int p = idx - WB_ELEMS;
        int q = (p >> 2) & 3;
        int h = (p >> 4) * 4 + (p & 3);
        int row = q * 512 + h;
        bias_p[p] = bih[row] + bhh[row];
    } else if (idx < WB_ELEMS + 2048 + 32768) {
        int i = idx - (WB_ELEMS + 2048);
        h0[i] = f2bf(h_prev[i]);
    } else if (idx < WB_ELEMS + 2048 + 32768 + 128) {
        cnts[idx - (WB_ELEMS + 2048 + 32768)] = 0u;
    }
}

// Optional: convert x to bf16 once (halves per-step x traffic, removes per-step cvt).
__global__ __launch_bounds__(256) void x_to_bf16(
    const float* __restrict__ x, u16* __restrict__ xb, int n8)
{
    int i = blockIdx.x * 256 + threadIdx.x;
    if (i < n8) {
        float4 fa = ((const float4*)x)[(size_t)i * 2];
        float4 fb = ((const float4*)x)[(size_t)i * 2 + 1];
        ((bf16x8*)xb)[i] = pack8(fa, fb);
    }
}

// Persistent LSTM. 128 blocks x 4 waves. Block b: batch-tile bt = b&3 (rows 16bt..),
// wave owns n-tile gt = (b>>2)*4 + wv (0..127) = hids 4gt..4gt+4, all 4 gates.
// Weights: 128 VGPR/lane, loaded once. c-state: 1 reg/lane. Per-step sync: 4
// independent groups of 32 blocks, monotonic counter at coherence point. NO cache
// fences: h exchanged via write-through (sc0 sc1) stores + coherent bypass loads.
__global__ __launch_bounds__(256, 1) void lstm_persist(
    const float* __restrict__ x_all, const u16* __restrict__ xbf, int xmode,
    const u16* __restrict__ WB, const float* __restrict__ bias_p,
    const float* __restrict__ c_prev,
    u16* __restrict__ h0, u16* __restrict__ h1, unsigned* __restrict__ cnts,
    float* __restrict__ out, float* __restrict__ hf, float* __restrict__ cf)
{
    const int tid  = threadIdx.x;
    const int lane = tid & 63;
    const int wv   = tid >> 6;
    const int b    = blockIdx.x;
    const int bt   = b & 3;
    const int gt   = (b >> 2) * 4 + wv;   // n-tile 0..127
    const int b0   = bt * 16;
    const int col  = lane & 15;
    const int quad = lane >> 4;
    const bool qa  = (col & 4) != 0;      // gate bit 0
    const bool qb  = (col & 8) != 0;      // gate bit 1
    const int q    = col >> 2;
    const int hl   = col & 3;

    unsigned* cnt = cnts + bt * 32;       // 128B-separated per group

    // ---- weights -> registers (once): 32 KB/wave = 128 VGPR/lane ----
    bf16x8 wx[16], wh[16];
    {
        const u16* wb = WB + (size_t)gt * (32 * 64 * 8) + lane * 8;
#pragma unroll
        for (int kc = 0; kc < 16; ++kc) {
            wx[kc] = *(const bf16x8*)(wb + (size_t)kc * 512);
            wh[kc] = *(const bf16x8*)(wb + (size_t)(kc + 16) * 512);
        }
    }

    const float bmy = bias_p[gt * 16 + col];
    const int hid   = gt * 4 + hl;
    const int myrow = quad * 4 + q;              // this lane's C-row within tile
    const int idx   = (b0 + myrow) * 512 + hid;  // cell index in [64][512]
    float c = c_prev[idx];

    const int ba = b0 + col;                     // A-frag row m = lane&15
    const u16* h0row = h0 + ba * 512 + quad * 8;
    const u16* h1row = h1 + ba * 512 + quad * 8;

    for (int t = 0; t < SS; ++t) {
        f32x4 acc = {0.f, 0.f, 0.f, 0.f};

        // ---- x-part (independent of recurrence; overlaps barrier slack) ----
        if (xmode) {
            const u16* xr = xbf + ((size_t)t * BB + ba) * 512 + quad * 8;
#pragma unroll
            for (int kc = 0; kc < 16; ++kc) {
                bf16x8 a = *(const bf16x8*)(xr + kc * 32);
                acc = __builtin_amdgcn_mfma_f32_16x16x32_bf16(a, wx[kc], acc, 0, 0, 0);
                if ((kc & 7) == 7) __builtin_amdgcn_sched_barrier(0);  // cap in-flight regs
            }
        } else {
            const float* xr = x_all + ((size_t)t * BB + ba) * 512 + quad * 8;
#pragma unroll
            for (int kc = 0; kc < 16; ++kc) {
                float4 fa = *(const float4*)(xr + kc * 32);
                float4 fb = *(const float4*)(xr + kc * 32 + 4);
                bf16x8 a = pack8(fa, fb);
                acc = __builtin_amdgcn_mfma_f32_16x16x32_bf16(a, wx[kc], acc, 0, 0, 0);
                if ((kc & 3) == 3) __builtin_amdgcn_sched_barrier(0);  // cap in-flight regs
            }
        }

        // ---- wait for h_{t-1}: 32 arrivals/group/step, counter at LLC ----
        if (t) {
            if (tid == 0) {
                const unsigned target = 32u * (unsigned)t;
                unsigned guard = 0;
                while (__hip_atomic_load(cnt, __ATOMIC_RELAXED, __HIP_MEMORY_SCOPE_AGENT) < target) {
                    if (++guard > (1u << 24)) break;   // fail loud, never deadlock
                }
            }
            __syncthreads();
        }

        // ---- h-part: coherent loads (bypass L1/L2 -> always fresh), then MFMA ----
        const u16* hr = ((t & 1) ? h1row : h0row);
        bf16x8 hA[16];
#pragma unroll
        for (int kc = 0; kc < 16; ++kc)
            load_coh_b128(&hA[kc], hr + kc * 32);
        asm volatile("s_waitcnt vmcnt(0)" ::: "memory");
        __builtin_amdgcn_sched_barrier(0);   // rule #18: keep MFMAs after the wait
#pragma unroll
        for (int kc = 0; kc < 16; ++kc)
            acc = __builtin_amdgcn_mfma_f32_16x16x32_bf16(hA[kc], wh[kc], acc, 0, 0, 0);

        // ---- epilogue: gather 4 gates per cell via 3 shfl_xor; 1 cell/lane ----
        float a0 = acc[0] + bmy, a1 = acc[1] + bmy, a2 = acc[2] + bmy, a3 = acc[3] + bmy;
        // send a[q^k] so partner (q^k) receives its gate at ITS row
        float s1 = qb ? (qa ? a2 : a3) : (qa ? a0 : a1);   // a[q^1]
        float s2 = qb ? (qa ? a1 : a0) : (qa ? a3 : a2);   // a[q^2]
        float s3 = qb ? (qa ? a0 : a1) : (qa ? a2 : a3);   // a[q^3]
        float v0 = qb ? (qa ? a3 : a2) : (qa ? a1 : a0);   // a[q] (own gate, own row)
        float v1 = __shfl_xor(s1, 4);                      // gate q^1 at my row
        float v2 = __shfl_xor(s2, 8);                      // gate q^2
        float v3 = __shfl_xor(s3, 12);                     // gate q^3
        // map {v0..v3} = gate q^k  ->  (i,f,g,o) = gates (0,1,2,3)
        float gi = qb ? (qa ? v3 : v2) : (qa ? v1 : v0);
        float gf = qb ? (qa ? v2 : v3) : (qa ? v0 : v1);
        float gg = qb ? (qa ? v1 : v0) : (qa ? v3 : v2);
        float go = qb ? (qa ? v0 : v1) : (qa ? v2 : v3);

        float i_ = 1.f / (1.f + __expf(-gi));
        float f_ = 1.f / (1.f + __expf(-gf));
        float g_ = 2.f / (1.f + __expf(-2.f * gg)) - 1.f;
        float o_ = 1.f / (1.f + __expf(-go));
        c = f_ * c + i_ * g_;
        float tc = 2.f / (1.f + __expf(-2.f * c)) - 1.f;
        float hnew = o_ * tc;

        // ---- stores: h write-through (agent-coherent), out non-temporal ----
        u16* hout = (t & 1) ? h0 : h1;
        __hip_atomic_store(hout + idx, f2bf(hnew), __ATOMIC_RELAXED, __HIP_MEMORY_SCOPE_AGENT);
        __builtin_nontemporal_store(hnew, out + (size_t)t * (BB * HH) + idx);
        if (t == SS - 1) { hf[idx] = hnew; cf[idx] = c; }

        // ---- arrive: drain stores (write-through acks at LLC), then bump ----
        asm volatile("s_waitcnt vmcnt(0)" ::: "memory");
        __syncthreads();
        if (tid == 0)
            __hip_atomic_fetch_add(cnt, 1u, __ATOMIC_RELAXED, __HIP_MEMORY_SCOPE_AGENT);
    }
}

extern "C" void kernel_launch(void* const* d_in, const int* in_sizes, int n_in,
                              void* d_out, int out_size, void* d_ws, size_t ws_size,
                              hipStream_t stream) {
    const float* x      = (const float*)d_in[0];
    const float* h_prev = (const float*)d_in[1];
    const float* c_prev = (const float*)d_in[2];
    const float* Wih    = (const float*)d_in[3];
    const float* Whh    = (const float*)d_in[4];
    const float* bih    = (const float*)d_in[5];
    const float* bhh    = (const float*)d_in[6];
    float* out = (float*)d_out;

    if (ws_size < WS_BASE) return;  // cannot run without scratch

    char* ws = (char*)d_ws;
    u16*      WB     = (u16*)ws;
    float*    bias_p = (float*)(ws + OFF_BIAS);
    u16*      h0     = (u16*)(ws + OFF_H0);
    u16*      h1     = (u16*)(ws + OFF_H1);
    unsigned* cnts   = (unsigned*)(ws + OFF_CNT);
    u16*      xbf    = (u16*)(ws + OFF_XBF);
    int xmode = (ws_size >= WS_XBF) ? 1 : 0;

    int prep_threads = WB_ELEMS + 2048 + 32768 + 128;
    int prep_blocks = (prep_threads + 255) / 256;
    hipLaunchKernelGGL(lstm_prep, dim3(prep_blocks), dim3(256), 0, stream,
                       Wih, Whh, bih, bhh, h_prev, WB, bias_p, h0, cnts);

    if (xmode) {
        int n8 = SS * BB * 512 / 8;          // 8.39M vector-8 chunks
        hipLaunchKernelGGL(x_to_bf16, dim3((n8 + 255) / 256), dim3(256), 0, stream,
                           x, xbf, n8);
    }

    float* hf = out + (size_t)SS * BB * HH;
    float* cf = hf + BB * HH;

    void* args[] = {
        (void*)&x, (void*)&xbf, (void*)&xmode, (void*)&WB, (void*)&bias_p,
        (void*)&c_prev, (void*)&h0, (void*)&h1, (void*)&cnts,
        (void*)&out, (void*)&hf, (void*)&cf
    };
    hipError_t err = hipLaunchCooperativeKernel(
        reinterpret_cast<void*>(lstm_persist), dim3(128), dim3(256), args, 0, stream);
    if (err != hipSuccess) {
        // 128 blocks x 256 thr = 1 block/CU on a 256-CU idle chip: co-resident anyway.
        hipLaunchKernelGGL(lstm_persist, dim3(128), dim3(256), 0, stream,
                           x, xbf, xmode, WB, bias_p, c_prev, h0, h1, cnts, out, hf, cf);
    }
}